// Round 9
// baseline (42.759 us; speedup 1.0000x reference)
//
#include <hip/hip_runtime.h>

typedef __bf16 bf16;
typedef __attribute__((ext_vector_type(4)))  __bf16 bf16x4;
typedef __attribute__((ext_vector_type(8)))  __bf16 bf16x8;
typedef __attribute__((ext_vector_type(4)))  float  f32x4;
typedef __attribute__((ext_vector_type(16))) float  f32x16;

constexpr int B_ = 16, N_ = 256, K_ = 10, C_ = 100, CP_ = 112;
constexpr float NL2E = -0.7213475204444817f;             // -0.5*log2(e)

__device__ inline bf16x8 cvt8(const float* p) {
    float4 a = *(const float4*)p, b = *(const float4*)(p + 4);
    bf16x8 r = {(bf16)a.x, (bf16)a.y, (bf16)a.z, (bf16)a.w,
                (bf16)b.x, (bf16)b.y, (bf16)b.z, (bf16)b.w};
    return r;
}
__device__ inline bf16x8 cvt4z(const float* p) {          // 4 valid + 4 zeros
    float4 a = *(const float4*)p;
    bf16x8 r = {(bf16)a.x, (bf16)a.y, (bf16)a.z, (bf16)a.w,
                (bf16)0.0f, (bf16)0.0f, (bf16)0.0f, (bf16)0.0f};
    return r;
}

// ---------------------------------------------------------------------------
// K1 (R8 verbatim): xkT[b,k][c(112)][m] via MFMA 32x32x16, wave = c-tile.
//   Rows c in [100,112) exactly 0. Grid 640 XCD-swizzled blocks.
// ---------------------------------------------------------------------------
__global__ __launch_bounds__(256) void xk_gemm(
    const float* __restrict__ x, const float* __restrict__ W,
    const float* __restrict__ bias, bf16* __restrict__ xkT)
{
    const int bid = blockIdx.x;
    const int xcd = bid & 7, s = bid >> 3;         // s: 0..79
    const int b  = xcd + 8 * (s / 40);
    const int rr = s % 40, kk = rr >> 2, mh = rr & 3;
    const int tid = threadIdx.x;
    const int w = tid >> 6, l = tid & 63, l31 = l & 31, h = l >> 5;
    const int c = w * 32 + l31;                    // A row this lane loads

    const bf16x8 zf = {(bf16)0.f,(bf16)0.f,(bf16)0.f,(bf16)0.f,
                       (bf16)0.f,(bf16)0.f,(bf16)0.f,(bf16)0.f};

    bf16x8 af[7];
    const float* Wrow = W + (size_t)c * C_;
    #pragma unroll
    for (int js = 0; js < 7; ++js) {
        const int jb = js * 16 + h * 8;
        af[js] = zf;
        if (c < C_) {
            if (jb + 8 <= C_)      af[js] = cvt8(Wrow + jb);
            else if (jb < C_)      af[js] = cvt4z(Wrow + jb);   // jb == 96
        }
    }

    f32x16 acc0, acc1;
    #pragma unroll
    for (int r = 0; r < 16; ++r) {
        int crow = w * 32 + (r & 3) + 8 * (r >> 2) + 4 * h;
        float bv = (crow < C_) ? bias[crow] : 0.0f;
        acc0[r] = bv; acc1[r] = bv;
    }

    const int m0 = mh * 64 + l31;
    const float* xp0 = x + ((size_t)(b * N_ + m0) * K_ + kk) * C_;
    const float* xp1 = x + ((size_t)(b * N_ + m0 + 32) * K_ + kk) * C_;
    #pragma unroll
    for (int js = 0; js < 7; ++js) {
        const int jb = js * 16 + h * 8;
        bf16x8 b0 = zf, b1 = zf;
        if (jb + 8 <= C_)      { b0 = cvt8(xp0 + jb);  b1 = cvt8(xp1 + jb); }
        else if (jb < C_)      { b0 = cvt4z(xp0 + jb); b1 = cvt4z(xp1 + jb); }
        acc0 = __builtin_amdgcn_mfma_f32_32x32x16_bf16(af[js], b0, acc0, 0, 0, 0);
        acc1 = __builtin_amdgcn_mfma_f32_32x32x16_bf16(af[js], b1, acc1, 0, 0, 0);
    }

    bf16* op = xkT + (size_t)(b * K_ + kk) * CP_ * N_ + mh * 64 + l31;
    #pragma unroll
    for (int r = 0; r < 16; ++r) {
        const int crow = w * 32 + (r & 3) + 8 * (r >> 2) + 4 * h;
        if (crow < CP_) {
            op[(size_t)crow * N_]      = (bf16)acc0[r];
            op[(size_t)crow * N_ + 32] = (bf16)acc1[r];
        }
    }
}

// ---------------------------------------------------------------------------
// K2: k-PAIR fused gaussian+GEMM. Block = (b, kp, n32) handles k0=kp, k1=kp+5.
//   Phase A: read pseudo/adj ONCE, build BOTH 32x256 ag tiles (8 exp2/iter)
//   into two 16KB XOR-swizzled LDS buffers. One barrier.
//   Phase B: fused MFMA loop - 2 independent acc chains (k0,k1) per wave,
//   32 x mfma_32x32x16, A via swizzled ds_read_b128, B gathered from xkT.
//   Pseudo logical traffic halves (160->80 MB); exp count unchanged.
// Grid 640 XCD-swizzled blocks x 256 thr; LDS 32KB.
// ---------------------------------------------------------------------------
__global__ __launch_bounds__(256) void gauss_agg(
    const float* __restrict__ adj, const float* __restrict__ pseudo,
    const float* __restrict__ mu, const float* __restrict__ sigma,
    const bf16* __restrict__ xkT, float* __restrict__ out)
{
    __shared__ __align__(16) char lds0[32 * 512];
    __shared__ __align__(16) char lds1[32 * 512];

    const int bid = blockIdx.x;
    const int xcd = bid & 7, s = bid >> 3;         // s: 0..79
    const int b  = xcd + 8 * (s / 40);
    const int rr = s % 40, kp = rr >> 3, nh = rr & 7;
    const int k0 = kp, k1 = kp + 5;
    const int n32 = nh * 32;
    const int tid = threadIdx.x;

    // coefs for both kernels (uniform -> scalar loads)
    float A0[4], B0[4], g0 = 0.0f, A1[4], B1[4], g1 = 0.0f;
    #pragma unroll
    for (int d = 0; d < 4; ++d) {
        float sg0 = sigma[k0 * 4 + d], mv0 = mu[k0 * 4 + d];
        float al0 = NL2E / (1e-6f + sg0 * sg0);
        A0[d] = al0; B0[d] = -2.0f * al0 * mv0; g0 += al0 * mv0 * mv0;
        float sg1 = sigma[k1 * 4 + d], mv1 = mu[k1 * 4 + d];
        float al1 = NL2E / (1e-6f + sg1 * sg1);
        A1[d] = al1; B1[d] = -2.0f * al1 * mv1; g1 += al1 * mv1 * mv1;
    }

    // ---- phase A: both ag tiles -> LDS, pseudo read once ----
    const float* pbase = pseudo + (size_t)(b * N_ + n32) * N_ * 4;
    const float* abase = adj    + (size_t)(b * N_ + n32) * N_;
    #pragma unroll 4
    for (int i = 0; i < 8; ++i) {
        const int idx = i * 256 + tid;             // 0..2047 quads
        const int row = idx >> 6;                  // 0..31
        const int m0  = (idx & 63) * 4;
        const float* pp = pbase + ((size_t)row * N_ + m0) * 4;
        float4 p0 = *(const float4*)(pp + 0);
        float4 p1 = *(const float4*)(pp + 4);
        float4 p2 = *(const float4*)(pp + 8);
        float4 p3 = *(const float4*)(pp + 12);
        float4 av = *(const float4*)(abase + (size_t)row * N_ + m0);

        float4 q0 = {p0.x*p0.x, p0.y*p0.y, p0.z*p0.z, p0.w*p0.w};
        float4 q1 = {p1.x*p1.x, p1.y*p1.y, p1.z*p1.z, p1.w*p1.w};
        float4 q2 = {p2.x*p2.x, p2.y*p2.y, p2.z*p2.z, p2.w*p2.w};
        float4 q3 = {p3.x*p3.x, p3.y*p3.y, p3.z*p3.z, p3.w*p3.w};

        float s00 = g0 + A0[0]*q0.x + B0[0]*p0.x + A0[1]*q0.y + B0[1]*p0.y
                       + A0[2]*q0.z + B0[2]*p0.z + A0[3]*q0.w + B0[3]*p0.w;
        float s01 = g0 + A0[0]*q1.x + B0[0]*p1.x + A0[1]*q1.y + B0[1]*p1.y
                       + A0[2]*q1.z + B0[2]*p1.z + A0[3]*q1.w + B0[3]*p1.w;
        float s02 = g0 + A0[0]*q2.x + B0[0]*p2.x + A0[1]*q2.y + B0[1]*p2.y
                       + A0[2]*q2.z + B0[2]*p2.z + A0[3]*q2.w + B0[3]*p2.w;
        float s03 = g0 + A0[0]*q3.x + B0[0]*p3.x + A0[1]*q3.y + B0[1]*p3.y
                       + A0[2]*q3.z + B0[2]*p3.z + A0[3]*q3.w + B0[3]*p3.w;

        float s10 = g1 + A1[0]*q0.x + B1[0]*p0.x + A1[1]*q0.y + B1[1]*p0.y
                       + A1[2]*q0.z + B1[2]*p0.z + A1[3]*q0.w + B1[3]*p0.w;
        float s11 = g1 + A1[0]*q1.x + B1[0]*p1.x + A1[1]*q1.y + B1[1]*p1.y
                       + A1[2]*q1.z + B1[2]*p1.z + A1[3]*q1.w + B1[3]*p1.w;
        float s12 = g1 + A1[0]*q2.x + B1[0]*p2.x + A1[1]*q2.y + B1[1]*p2.y
                       + A1[2]*q2.z + B1[2]*p2.z + A1[3]*q2.w + B1[3]*p2.w;
        float s13 = g1 + A1[0]*q3.x + B1[0]*p3.x + A1[1]*q3.y + B1[1]*p3.y
                       + A1[2]*q3.z + B1[2]*p3.z + A1[3]*q3.w + B1[3]*p3.w;

        bf16x4 o0 = {(bf16)(__builtin_amdgcn_exp2f(s00) * av.x),
                     (bf16)(__builtin_amdgcn_exp2f(s01) * av.y),
                     (bf16)(__builtin_amdgcn_exp2f(s02) * av.z),
                     (bf16)(__builtin_amdgcn_exp2f(s03) * av.w)};
        bf16x4 o1 = {(bf16)(__builtin_amdgcn_exp2f(s10) * av.x),
                     (bf16)(__builtin_amdgcn_exp2f(s11) * av.y),
                     (bf16)(__builtin_amdgcn_exp2f(s12) * av.z),
                     (bf16)(__builtin_amdgcn_exp2f(s13) * av.w)};

        const int ch = m0 >> 3, half = (m0 >> 2) & 1;
        const int off = row * 512 + ((ch ^ (row & 7)) * 16) + half * 8;
        *(bf16x4*)(lds0 + off) = o0;
        *(bf16x4*)(lds1 + off) = o1;
    }
    __syncthreads();

    // ---- phase B: fused dual-k MFMA ----
    const int w = tid >> 6, l = tid & 63, l31 = l & 31, h = l >> 5;
    const bf16* brow0 = xkT + (size_t)(b * K_ + k0) * CP_ * N_ + (size_t)(w * 32 + l31) * N_;
    const bf16* brow1 = xkT + (size_t)(b * K_ + k1) * CP_ * N_ + (size_t)(w * 32 + l31) * N_;

    f32x16 acc0, acc1;
    #pragma unroll
    for (int i = 0; i < 16; ++i) { acc0[i] = 0.0f; acc1[i] = 0.0f; }

    #pragma unroll
    for (int ks = 0; ks < 16; ++ks) {
        const int m0 = ks * 16 + h * 8;
        const int off = l31 * 512 + (((ks * 2 + h) ^ (l31 & 7)) * 16);
        bf16x8 af0 = *(const bf16x8*)(lds0 + off);
        bf16x8 af1 = *(const bf16x8*)(lds1 + off);
        bf16x8 bf0 = *(const bf16x8*)(brow0 + m0);
        bf16x8 bf1 = *(const bf16x8*)(brow1 + m0);
        acc0 = __builtin_amdgcn_mfma_f32_32x32x16_bf16(af0, bf0, acc0, 0, 0, 0);
        acc1 = __builtin_amdgcn_mfma_f32_32x32x16_bf16(af1, bf1, acc1, 0, 0, 0);
    }

    const int c = w * 32 + l31;
    if (c < C_) {
        float* ob0 = out + (size_t)(b * K_ + k0) * C_ * N_ + (size_t)c * N_ + n32;
        float* ob1 = out + (size_t)(b * K_ + k1) * C_ * N_ + (size_t)c * N_ + n32;
        #pragma unroll
        for (int q = 0; q < 4; ++q) {
            float4 v0 = {acc0[4*q+0], acc0[4*q+1], acc0[4*q+2], acc0[4*q+3]};
            float4 v1 = {acc1[4*q+0], acc1[4*q+1], acc1[4*q+2], acc1[4*q+3]};
            *(float4*)(ob0 + 8 * q + 4 * h) = v0;
            *(float4*)(ob1 + 8 * q + 4 * h) = v1;
        }
    }
}

extern "C" void kernel_launch(void* const* d_in, const int* in_sizes, int n_in,
                              void* d_out, int out_size, void* d_ws, size_t ws_size,
                              hipStream_t stream)
{
    const float* x      = (const float*)d_in[0];
    const float* adj    = (const float*)d_in[1];
    const float* pseudo = (const float*)d_in[2];
    const float* mu     = (const float*)d_in[3];
    const float* sigma  = (const float*)d_in[4];
    const float* W      = (const float*)d_in[5];
    const float* bias   = (const float*)d_in[6];
    float* out = (float*)d_out;
    bf16* xkT  = (bf16*)d_ws;                      // 9.18 MB

    hipLaunchKernelGGL(xk_gemm, dim3(640), dim3(256), 0, stream, x, W, bias, xkT);
    hipLaunchKernelGGL(gauss_agg, dim3(640), dim3(256), 0, stream,
                       adj, pseudo, mu, sigma, xkT, out);
}